// Round 4
// baseline (405.521 us; speedup 1.0000x reference)
//
#include <hip/hip_runtime.h>

#define HWB   3136
#define HWPAD 3200
#define SPAD  3364   // 58*58 zero-padded spatial

typedef __attribute__((ext_vector_type(8))) short bf16x8;
typedef __attribute__((ext_vector_type(4))) float f32x4;

__device__ __forceinline__ unsigned short f2bf(float f) {
    unsigned u = __float_as_uint(f);
    unsigned r = (u + 0x7fffu + ((u >> 16) & 1u)) >> 16;
    return (unsigned short)r;
}
__device__ __forceinline__ float bf2f(unsigned short h) {
    return __uint_as_float(((unsigned)h) << 16);
}
__device__ __forceinline__ void gl_lds16(const void* g, void* l) {
    __builtin_amdgcn_global_load_lds(
        (const __attribute__((address_space(1))) void*)g,
        (__attribute__((address_space(3))) void*)l, 16, 0, 0);
}

// ---------------------------------------------------------------------------
// Prep: x [32][256][3136] f32 -> xc bf16 (same layout, vectorized stores)
//                             -> xp [32][3364][256] bf16 (padded channels-last)
// 64c x 64s tile per block; LDS transpose with stride-66 padding.
// ---------------------------------------------------------------------------
__global__ __launch_bounds__(256) void k_prep(
    const float* __restrict__ x, unsigned short* __restrict__ xc,
    unsigned short* __restrict__ xp)
{
    __shared__ short tile[64 * 66];
    const int n = blockIdx.z, c0 = blockIdx.y * 64, s0 = blockIdx.x * 64;
    const int t = threadIdx.x;
    const int cl = t >> 2;              // 0..63 local channel
    const int sq = (t & 3) * 16;        // 0/16/32/48 local spatial offset

    const float* src = x + ((size_t)(n * 256 + c0 + cl)) * HWB + s0 + sq;
    unsigned short bf[16];
#pragma unroll
    for (int j = 0; j < 4; ++j) {
        float4 v = *(const float4*)(src + j * 4);
        bf[j * 4 + 0] = f2bf(v.x); bf[j * 4 + 1] = f2bf(v.y);
        bf[j * 4 + 2] = f2bf(v.z); bf[j * 4 + 3] = f2bf(v.w);
    }
    unsigned short* xcb = xc + ((size_t)(n * 256 + c0 + cl)) * HWB + s0 + sq;
    *(bf16x8*)xcb = *(const bf16x8*)&bf[0];
    *(bf16x8*)(xcb + 8) = *(const bf16x8*)&bf[8];
#pragma unroll
    for (int k = 0; k < 16; ++k)
        tile[(sq + k) * 66 + cl] = (short)bf[k];
    __syncthreads();
    const int r = t >> 2;               // s_local 0..63
    const int cq = (t & 3) * 16;        // channel chunk 0/16/32/48
    unsigned short ob[16];
#pragma unroll
    for (int j = 0; j < 8; ++j) {
        unsigned w = *(const unsigned*)&tile[r * 66 + cq + 2 * j];
        ob[2 * j] = (unsigned short)w;
        ob[2 * j + 1] = (unsigned short)(w >> 16);
    }
    const int s = s0 + r;
    const int sp = s + 2 * (s / 56) + 59;   // (y+1)*58 + (x+1)
    unsigned short* dst = xp + ((size_t)n * SPAD + sp) * 256 + c0 + cq;
    *(bf16x8*)dst = *(const bf16x8*)&ob[0];
    *(bf16x8*)(dst + 8) = *(const bf16x8*)&ob[8];
}

// ---------------------------------------------------------------------------
// Zero the 228 border rows of xp per image, coalesced 16B chunks.
// ---------------------------------------------------------------------------
__global__ __launch_bounds__(256) void k_zero(
    unsigned short* __restrict__ xp)
{
    const int n = blockIdx.y;
    const int idx = blockIdx.x * 256 + threadIdx.x;
    if (idx >= 228 * 32) return;
    const int i = idx >> 5, ch = idx & 31;
    int sp;
    if (i < 58)       sp = i;                        // y = 0
    else if (i < 116) sp = 3306 + (i - 58);          // y = 57
    else if (i < 172) sp = (i - 115) * 58;           // x = 0, y = 1..56
    else              sp = (i - 171) * 58 + 57;      // x = 57, y = 1..56
    bf16x8 z = {};
    *(bf16x8*)&xp[((size_t)n * SPAD + sp) * 256 + ch * 8] = z;
}

// ---------------------------------------------------------------------------
// Prep B: p1 [3136][256] f32 -> p1t [256][3136] bf16
// ---------------------------------------------------------------------------
__global__ __launch_bounds__(256) void k_prep_p1t(
    const float* __restrict__ p1, unsigned short* __restrict__ p1t)
{
    __shared__ unsigned short tile[32][33];
    const int e0 = blockIdx.y * 32, h0 = blockIdx.x * 32;
    const int lx = threadIdx.x & 31, ly = threadIdx.x >> 5;
#pragma unroll
    for (int it = 0; it < 4; ++it) {
        int lh = ly + it * 8;
        tile[lh][lx] = f2bf(p1[(size_t)(h0 + lh) * 256 + e0 + lx]);
    }
    __syncthreads();
#pragma unroll
    for (int it = 0; it < 4; ++it) {
        int le = ly + it * 8;
        p1t[(size_t)(e0 + le) * HWB + h0 + lx] = tile[lx][le];
    }
}

// ---------------------------------------------------------------------------
// Prep C: conv_w [256][128][9] f32 -> wpack [256][tap*128+ci] bf16.
// ---------------------------------------------------------------------------
__global__ __launch_bounds__(256) void k_prep_w(
    const float* __restrict__ w, unsigned short* __restrict__ wp)
{
    const int o = blockIdx.x, t = threadIdx.x;
#pragma unroll
    for (int k = t; k < 1152; k += 256) {
        int tap = k >> 7, ci = k & 127;
        wp[(size_t)o * 1152 + k] = f2bf(w[(size_t)o * 1152 + ci * 9 + tap]);
    }
}

// ---------------------------------------------------------------------------
// GEMM1 (split-K=4, BK=64): part[z][m][e] = sum_k xc[m][k] p1t[e][k]
// Double-buffered staging; XCD swizzle.  z=0 -> 13 steps, z=1..3 -> 12.
// ---------------------------------------------------------------------------
__global__ __launch_bounds__(256) void k_gemm1(
    const unsigned short* __restrict__ xc, const unsigned short* __restrict__ p1t,
    float* __restrict__ part)
{
    __shared__ short As[2][128 * 64];
    __shared__ short Bs[2][128 * 64];
    const int tid = threadIdx.x;
    const int orig = blockIdx.x;                      // 512 = 8 * 64
    const int wgid = (orig & 7) * 64 + (orig >> 3);
    const int z = wgid >> 7;
    const int rem = wgid & 127;
    const int tileM = (rem >> 1) * 128;
    const int tileN = (rem & 1) * 128;
    const int kbase = z ? (832 + (z - 1) * 768) : 0;
    const int nk = z ? 12 : 13;
    const int wave = tid >> 6, lane = tid & 63;
    const int wm = (wave >> 1) * 64, wn = (wave & 1) * 64;

    const int rl = tid >> 3, q = tid & 7;
    const int swq = (q ^ (rl & 7)) * 8;
    const unsigned short* asrc = xc + (size_t)(tileM + rl) * HWB + kbase + swq;
    const unsigned short* bsrc = p1t + (size_t)(tileN + rl) * HWB + kbase + swq;

    f32x4 acc[4][4] = {};
    const int frow = lane & 15, quad = lane >> 4, sw = frow & 7;
    const int ldst = rl * 64 + q * 8;

#pragma unroll
    for (int p = 0; p < 4; ++p) {
        gl_lds16(asrc + (size_t)(p * 32) * HWB, &As[0][p * 2048 + ldst]);
        gl_lds16(bsrc + (size_t)(p * 32) * HWB, &Bs[0][p * 2048 + ldst]);
    }
    __syncthreads();

    int cur = 0;
    for (int i2 = 0; i2 < nk; ++i2) {
        if (i2 + 1 < nk) {
            const int kn = (i2 + 1) * 64;
#pragma unroll
            for (int p = 0; p < 4; ++p) {
                gl_lds16(asrc + (size_t)(p * 32) * HWB + kn, &As[cur ^ 1][p * 2048 + ldst]);
                gl_lds16(bsrc + (size_t)(p * 32) * HWB + kn, &Bs[cur ^ 1][p * 2048 + ldst]);
            }
        }
        const short* Ab = As[cur];
        const short* Bb = Bs[cur];
#pragma unroll
        for (int h = 0; h < 2; ++h) {
            bf16x8 af[4], bfr[4];
#pragma unroll
            for (int i = 0; i < 4; ++i)
                af[i] = *(const bf16x8*)&Ab[(wm + i * 16 + frow) * 64 + ((h * 4 + quad) ^ sw) * 8];
#pragma unroll
            for (int j = 0; j < 4; ++j)
                bfr[j] = *(const bf16x8*)&Bb[(wn + j * 16 + frow) * 64 + ((h * 4 + quad) ^ sw) * 8];
#pragma unroll
            for (int i = 0; i < 4; ++i)
#pragma unroll
                for (int j = 0; j < 4; ++j)
                    acc[i][j] = __builtin_amdgcn_mfma_f32_16x16x32_bf16(af[i], bfr[j], acc[i][j], 0, 0, 0);
        }
        __syncthreads();
        cur ^= 1;
    }
    float* ob = part + (size_t)z * 8192 * 256;
#pragma unroll
    for (int j = 0; j < 4; ++j) {
        const int e = tileN + wn + j * 16 + (lane & 15);
#pragma unroll
        for (int i = 0; i < 4; ++i)
#pragma unroll
            for (int r = 0; r < 4; ++r) {
                int m = tileM + wm + i * 16 + (lane >> 4) * 4 + r;
                ob[(size_t)m * 256 + e] = acc[i][j][r];
            }
    }
}

// ---------------------------------------------------------------------------
// t4scale: reduce 4 split-K slabs; t4h[m][e] = bf16(t1*p4); t5[m]=sum_e t4*p5
// ---------------------------------------------------------------------------
__global__ __launch_bounds__(256) void k_t4scale(
    const float* __restrict__ part, const float* __restrict__ p4,
    const float* __restrict__ p5, unsigned short* __restrict__ t4h,
    float* __restrict__ t5)
{
    const int row = blockIdx.x * 4 + (threadIdx.x >> 6);
    const int lane = threadIdx.x & 63;
    const size_t off = (size_t)row * 256 + lane * 4;
    const size_t slab = (size_t)8192 * 256;
    float4 a0 = *(const float4*)&part[off];
    float4 a1 = *(const float4*)&part[off + slab];
    float4 a2 = *(const float4*)&part[off + 2 * slab];
    float4 a3 = *(const float4*)&part[off + 3 * slab];
    float4 a;
    a.x = (a0.x + a1.x) + (a2.x + a3.x);
    a.y = (a0.y + a1.y) + (a2.y + a3.y);
    a.z = (a0.z + a1.z) + (a2.z + a3.z);
    a.w = (a0.w + a1.w) + (a2.w + a3.w);
    float4 sc = *(const float4*)&p4[(size_t)(row & 255) * 256 + lane * 4];
    float4 pv = *(const float4*)&p5[lane * 4];
    float v0 = a.x * sc.x, v1 = a.y * sc.y, v2 = a.z * sc.z, v3 = a.w * sc.w;
    ushort4 o;
    o.x = f2bf(v0); o.y = f2bf(v1); o.z = f2bf(v2); o.w = f2bf(v3);
    *(ushort4*)&t4h[(size_t)row * 256 + lane * 4] = o;
    float sum = v0 * pv.x + v1 * pv.y + v2 * pv.z + v3 * pv.w;
#pragma unroll
    for (int offd = 32; offd > 0; offd >>= 1) sum += __shfl_down(sum, offd);
    if (lane == 0) t5[row] = sum;
}

// ---------------------------------------------------------------------------
// t7[n][s] += 0.0625 * sum_{c in 32-chunk} t5[n*256+c] * xc[n][c][s]
// ---------------------------------------------------------------------------
__global__ __launch_bounds__(256) void k_t7(
    const unsigned short* __restrict__ xc, const float* __restrict__ t5,
    float* __restrict__ t7)
{
    const int n = blockIdx.z;
    const int c0 = blockIdx.y * 32;
    const int s0 = blockIdx.x * 1568;
    __shared__ float wv[32];
    const int t = threadIdx.x;
    if (t < 32) wv[t] = t5[n * 256 + c0 + t];
    __syncthreads();
    if (t >= 196) return;
    const unsigned short* base = xc + ((size_t)(n * 256 + c0)) * HWB + s0 + t * 8;
    float acc[8] = {};
    for (int c = 0; c < 32; ++c) {
        bf16x8 v = *(const bf16x8*)(base + (size_t)c * HWB);
        float w = wv[c];
#pragma unroll
        for (int j = 0; j < 8; ++j)
            acc[j] += w * bf2f((unsigned short)v[j]);
    }
    float* dst = t7 + (size_t)n * HWB + s0 + t * 8;
#pragma unroll
    for (int j = 0; j < 8; ++j)
        atomicAdd(&dst[j], acc[j] * 0.0625f);
}

// ---------------------------------------------------------------------------
// FUSED conv+bmm per (n, tileS=128):
//   Phase 1 (x2 groups): t3 tile [128s][128o] = conv GEMM (K=1152),
//     result bf16 -> LDS t3t[128][256] with per-row XOR-chunk swizzle.
//   Phase 2: out[n][a][tileS..] = t4h[n] (256x256) @ t3t^T / 16 + t7.
// t3 never touches HBM.  LDS = 64KB stage + 64KB t3t -> 1 block/CU.
// ---------------------------------------------------------------------------
__global__ __launch_bounds__(256) void k_convbmm(
    const unsigned short* __restrict__ xp, const unsigned short* __restrict__ wp,
    const unsigned short* __restrict__ t4h, const float* __restrict__ t7,
    float* __restrict__ out)
{
    __shared__ short stg[32768];        // 64 KB: conv A0|A1|B0|B1 (8192 each)
    __shared__ short t3t[32768];        // 64 KB: [128 s][256 o] swizzled
    const int tid = threadIdx.x;
    const int orig = blockIdx.x;                      // 800 = 8 * 100
    const int wgid = (orig & 7) * 100 + (orig >> 3);  // bijective XCD chunks
    const int n = wgid / 25;
    const int tileS = (wgid - n * 25) * 128;
    const int wave = tid >> 6, lane = tid & 63;

    const int rl = tid >> 3, q = tid & 7;
    const int swq = (q ^ (rl & 7)) * 8;
    const int ldst = rl * 64 + q * 8;
    const int frow = lane & 15, quad = lane >> 4, sw = frow & 7;

    // ---- phase 1: grouped conv into t3t ----
    const int wm = (wave >> 1) * 64, wn = (wave & 1) * 64;
    int rofA[4], rofB[4];
#pragma unroll
    for (int i = 0; i < 4; ++i) {
        rofA[i] = (wm + i * 16 + frow) * 64;
        rofB[i] = (wn + i * 16 + frow) * 64;
    }
    int sp4[4];
#pragma unroll
    for (int p = 0; p < 4; ++p) {
        int s = tileS + p * 32 + rl;
        int sc = s < HWB ? s : HWB - 1;     // clamped rows feed discarded outputs
        sp4[p] = sc + 2 * (sc / 56) + 59;
    }

    for (int g = 0; g < 2; ++g) {
        const unsigned short* xpn = xp + (size_t)n * SPAD * 256 + g * 128 + swq;
        const unsigned short* arow[4];
        const unsigned short* brow[4];
#pragma unroll
        for (int p = 0; p < 4; ++p) {
            arow[p] = xpn + (size_t)sp4[p] * 256;
            brow[p] = wp + (size_t)(g * 128 + p * 32 + rl) * 1152 + swq;
        }
        f32x4 acc[4][4] = {};
        // prologue: stage t=0 into buffer 0
        {
            const int shift0 = (-59) * 256;
#pragma unroll
            for (int p = 0; p < 4; ++p) {
                gl_lds16(arow[p] + shift0, &stg[p * 2048 + ldst]);
                gl_lds16(brow[p], &stg[16384 + p * 2048 + ldst]);
            }
        }
        __syncthreads();
        int cur = 0;
#pragma unroll
        for (int t = 0; t < 18; ++t) {
            if (t < 17) {
                const int tn = t + 1;
                const int tap = tn >> 1;
                const int shift = ((tap / 3 - 1) * 58 + (tap % 3 - 1)) * 256 + (tn & 1) * 64;
#pragma unroll
                for (int p = 0; p < 4; ++p) {
                    gl_lds16(arow[p] + shift, &stg[(cur ^ 1) * 8192 + p * 2048 + ldst]);
                    gl_lds16(brow[p] + tn * 64, &stg[16384 + (cur ^ 1) * 8192 + p * 2048 + ldst]);
                }
            }
            const short* Ab = &stg[cur * 8192];
            const short* Bb = &stg[16384 + cur * 8192];
#pragma unroll
            for (int h = 0; h < 2; ++h) {
                bf16x8 af[4], bfr[4];
#pragma unroll
                for (int i = 0; i < 4; ++i)
                    af[i] = *(const bf16x8*)&Ab[rofA[i] + ((h * 4 + quad) ^ sw) * 8];
#pragma unroll
                for (int j = 0; j < 4; ++j)
                    bfr[j] = *(const bf16x8*)&Bb[rofB[j] + ((h * 4 + quad) ^ sw) * 8];
#pragma unroll
                for (int i = 0; i < 4; ++i)
#pragma unroll
                    for (int j = 0; j < 4; ++j)
                        acc[i][j] = __builtin_amdgcn_mfma_f32_16x16x32_bf16(af[i], bfr[j], acc[i][j], 0, 0, 0);
            }
            __syncthreads();
            cur ^= 1;
        }
        // epilogue: acc -> t3t (bf16, XOR-chunk swizzle per row)
#pragma unroll
        for (int i = 0; i < 4; ++i)
#pragma unroll
            for (int r = 0; r < 4; ++r) {
                const int sLoc = wm + i * 16 + quad * 4 + r;
                const bool vs = (tileS + sLoc) < HWB;
                const int key = sLoc & 7;
#pragma unroll
                for (int j = 0; j < 4; ++j) {
                    const int oc = g * 128 + wn + j * 16 + frow;
                    const int addr = sLoc * 256 + (((oc >> 3) ^ key) << 3) + (oc & 7);
                    t3t[addr] = (short)f2bf(vs ? acc[i][j][r] : 0.f);
                }
            }
    }

    // ---- phase 2: bmm  D[256a][128s] = t4h[n] @ t3t^T ----
    const int wm2 = wave * 64;
    f32x4 acc2[4][8] = {};
    const unsigned short* a2src = t4h + ((size_t)n * 256 + rl) * 256 + swq;

    // prologue: stage k0=0 into bmm buffer 0 (stg[0..16383])
#pragma unroll
    for (int p = 0; p < 8; ++p)
        gl_lds16(a2src + (size_t)(p * 32) * 256, &stg[p * 2048 + ldst]);
    __syncthreads();   // also makes all t3t writes visible

    int d = 0;
#pragma unroll
    for (int k0 = 0; k0 < 256; k0 += 64) {
        if (k0 < 192) {
#pragma unroll
            for (int p = 0; p < 8; ++p)
                gl_lds16(a2src + (size_t)(p * 32) * 256 + k0 + 64,
                         &stg[(d ^ 1) * 16384 + p * 2048 + ldst]);
        }
        const short* Ab2 = &stg[d * 16384];
#pragma unroll
        for (int h = 0; h < 2; ++h) {
            const int kc8 = (k0 >> 3) + h * 4 + quad;
            bf16x8 af[4], bfr[8];
#pragma unroll
            for (int i = 0; i < 4; ++i)
                af[i] = *(const bf16x8*)&Ab2[(wm2 + i * 16 + frow) * 64 + ((h * 4 + quad) ^ sw) * 8];
#pragma unroll
            for (int j = 0; j < 8; ++j)
                bfr[j] = *(const bf16x8*)&t3t[(j * 16 + frow) * 256 + ((kc8 ^ sw) << 3)];
#pragma unroll
            for (int i = 0; i < 4; ++i)
#pragma unroll
                for (int j = 0; j < 8; ++j)
                    acc2[i][j] = __builtin_amdgcn_mfma_f32_16x16x32_bf16(af[i], bfr[j], acc2[i][j], 0, 0, 0);
        }
        __syncthreads();
        d ^= 1;
    }

    const float* t7n = t7 + (size_t)n * HWB;
    float* ob = out + (size_t)n * 256 * HWB;
#pragma unroll
    for (int j = 0; j < 8; ++j) {
        const int s = tileS + j * 16 + frow;
        if (s >= HWB) continue;
        const float t7v = t7n[s];
#pragma unroll
        for (int i = 0; i < 4; ++i)
#pragma unroll
            for (int r = 0; r < 4; ++r) {
                const int a = wm2 + i * 16 + quad * 4 + r;
                ob[(size_t)a * HWB + s] = acc2[i][j][r] * 0.0625f + t7v;
            }
    }
}

extern "C" void kernel_launch(void* const* d_in, const int* in_sizes, int n_in,
                              void* d_out, int out_size, void* d_ws, size_t ws_size,
                              hipStream_t stream) {
    const float* x  = (const float*)d_in[0];
    const float* p1 = (const float*)d_in[1];
    const float* cw = (const float*)d_in[2];
    const float* p4 = (const float*)d_in[3];
    const float* p5 = (const float*)d_in[4];

    char* w = (char*)d_ws;
    unsigned short* xp    = (unsigned short*)w;  w += (size_t)32 * SPAD * 256 * 2;   // 55.1 MB
    unsigned short* p1t   = (unsigned short*)w;  w += (size_t)256 * HWB * 2;
    unsigned short* wpack = (unsigned short*)w;  w += (size_t)256 * 1152 * 2;
    unsigned short* t4h   = (unsigned short*)w;  w += (size_t)8192 * 256 * 2;
    float* t5             = (float*)w;           w += (size_t)8192 * 4;
    float* t7             = (float*)w;           w += (size_t)32 * HWB * 4;

    // d_out doubles as scratch; all scratch consumers finish before k_convbmm
    // overwrites it with the real output:
    //   xc   [32][256][3136] bf16 = 51,380,224 B
    //   part [4][8192][256]  f32  = 33,554,432 B  (total 84.9 MB <= 102.8 MB)
    char* o = (char*)d_out;
    unsigned short* xc = (unsigned short*)o;
    float* part        = (float*)(o + (size_t)32 * 256 * HWB * 2);
    float* out = (float*)d_out;

    hipMemsetAsync(t7, 0, (size_t)32 * HWB * 4, stream);
    k_prep    <<<dim3(49, 4, 32), 256, 0, stream>>>(x, xc, xp);
    k_zero    <<<dim3(29, 32),    256, 0, stream>>>(xp);
    k_prep_p1t<<<dim3(98, 8),     256, 0, stream>>>(p1, p1t);
    k_prep_w  <<<dim3(256),       256, 0, stream>>>(cw, wpack);
    k_gemm1   <<<dim3(512),       256, 0, stream>>>(xc, p1t, part);
    k_t4scale <<<dim3(2048),      256, 0, stream>>>(part, p4, p5, t4h, t5);
    k_t7      <<<dim3(2, 8, 32),  256, 0, stream>>>(xc, t5, t7);
    k_convbmm <<<dim3(800),       256, 0, stream>>>(xp, wpack, t4h, t7, out);
}

// Round 5
// 344.640 us; speedup vs baseline: 1.1767x; 1.1767x over previous
//
#include <hip/hip_runtime.h>

#define HWB   3136
#define HWPAD 3200
#define SPAD  3364   // 58*58 zero-padded spatial

typedef __attribute__((ext_vector_type(8))) short bf16x8;
typedef __attribute__((ext_vector_type(4))) float f32x4;

__device__ __forceinline__ unsigned short f2bf(float f) {
    unsigned u = __float_as_uint(f);
    unsigned r = (u + 0x7fffu + ((u >> 16) & 1u)) >> 16;
    return (unsigned short)r;
}
__device__ __forceinline__ float bf2f(unsigned short h) {
    return __uint_as_float(((unsigned)h) << 16);
}
__device__ __forceinline__ void gl_lds16(const void* g, void* l) {
    __builtin_amdgcn_global_load_lds(
        (const __attribute__((address_space(1))) void*)g,
        (__attribute__((address_space(3))) void*)l, 16, 0, 0);
}

// ---------------------------------------------------------------------------
// Prep: x [32][256][3136] f32 -> xc bf16 (same layout, vectorized stores)
//                             -> xp [32][3364][256] bf16 (padded channels-last)
// 64c x 64s tile per block; LDS transpose with stride-66 padding.
// ---------------------------------------------------------------------------
__global__ __launch_bounds__(256) void k_prep(
    const float* __restrict__ x, unsigned short* __restrict__ xc,
    unsigned short* __restrict__ xp)
{
    __shared__ short tile[64 * 66];
    const int n = blockIdx.z, c0 = blockIdx.y * 64, s0 = blockIdx.x * 64;
    const int t = threadIdx.x;
    const int cl = t >> 2;              // 0..63 local channel
    const int sq = (t & 3) * 16;        // 0/16/32/48 local spatial offset

    const float* src = x + ((size_t)(n * 256 + c0 + cl)) * HWB + s0 + sq;
    unsigned short bf[16];
#pragma unroll
    for (int j = 0; j < 4; ++j) {
        float4 v = *(const float4*)(src + j * 4);
        bf[j * 4 + 0] = f2bf(v.x); bf[j * 4 + 1] = f2bf(v.y);
        bf[j * 4 + 2] = f2bf(v.z); bf[j * 4 + 3] = f2bf(v.w);
    }
    unsigned short* xcb = xc + ((size_t)(n * 256 + c0 + cl)) * HWB + s0 + sq;
    *(bf16x8*)xcb = *(const bf16x8*)&bf[0];
    *(bf16x8*)(xcb + 8) = *(const bf16x8*)&bf[8];
#pragma unroll
    for (int k = 0; k < 16; ++k)
        tile[(sq + k) * 66 + cl] = (short)bf[k];
    __syncthreads();
    const int r = t >> 2;               // s_local 0..63
    const int cq = (t & 3) * 16;        // channel chunk 0/16/32/48
    unsigned short ob[16];
#pragma unroll
    for (int j = 0; j < 8; ++j) {
        unsigned w = *(const unsigned*)&tile[r * 66 + cq + 2 * j];
        ob[2 * j] = (unsigned short)w;
        ob[2 * j + 1] = (unsigned short)(w >> 16);
    }
    const int s = s0 + r;
    const int sp = s + 2 * (s / 56) + 59;   // (y+1)*58 + (x+1)
    unsigned short* dst = xp + ((size_t)n * SPAD + sp) * 256 + c0 + cq;
    *(bf16x8*)dst = *(const bf16x8*)&ob[0];
    *(bf16x8*)(dst + 8) = *(const bf16x8*)&ob[8];
}

// ---------------------------------------------------------------------------
// Merged small prep: [0,784) p1t transpose; [784,1040) wpack; [1040,1968)
// xp border zeroing.  All independent.
// ---------------------------------------------------------------------------
__global__ __launch_bounds__(256) void k_misc(
    const float* __restrict__ p1, const float* __restrict__ cw,
    unsigned short* __restrict__ p1t, unsigned short* __restrict__ wp,
    unsigned short* __restrict__ xp)
{
    const int b = blockIdx.x, t = threadIdx.x;
    if (b < 784) {
        __shared__ unsigned short tile[32][33];
        const int h0 = (b % 98) * 32, e0 = (b / 98) * 32;
        const int lx = t & 31, ly = t >> 5;
#pragma unroll
        for (int it = 0; it < 4; ++it) {
            int lh = ly + it * 8;
            tile[lh][lx] = f2bf(p1[(size_t)(h0 + lh) * 256 + e0 + lx]);
        }
        __syncthreads();
#pragma unroll
        for (int it = 0; it < 4; ++it) {
            int le = ly + it * 8;
            p1t[(size_t)(e0 + le) * HWB + h0 + lx] = tile[lx][le];
        }
    } else if (b < 1040) {
        const int o = b - 784;
#pragma unroll
        for (int k = t; k < 1152; k += 256) {
            int tap = k >> 7, ci = k & 127;
            wp[(size_t)o * 1152 + k] = f2bf(cw[(size_t)o * 1152 + ci * 9 + tap]);
        }
    } else {
        const int bb = b - 1040;            // 0..927 = 32n * 29chunks
        const int n = bb / 29, xb = bb - n * 29;
        const int idx = xb * 256 + t;
        if (idx < 228 * 32) {
            const int i = idx >> 5, ch = idx & 31;
            int sp;
            if (i < 58)       sp = i;                        // y = 0
            else if (i < 116) sp = 3306 + (i - 58);          // y = 57
            else if (i < 172) sp = (i - 115) * 58;           // x = 0
            else              sp = (i - 171) * 58 + 57;      // x = 57
            bf16x8 z = {};
            *(bf16x8*)&xp[((size_t)n * SPAD + sp) * 256 + ch * 8] = z;
        }
    }
}

// ---------------------------------------------------------------------------
// Conv (grouped 3x3) MFMA GEMM per (n,g): D[m=s][n=o], K = 9 taps * 128 ci.
// XCD-swizzled grid; double-buffered LDS; one barrier per K-step.
// ---------------------------------------------------------------------------
__global__ __launch_bounds__(256) void k_conv(
    const unsigned short* __restrict__ xp, const unsigned short* __restrict__ wp,
    unsigned short* __restrict__ t3cl)
{
    __shared__ short As[2][128 * 64];
    __shared__ short Bs[2][128 * 64];
    const int tid = threadIdx.x;
    const int orig = blockIdx.x;                       // 1600 = 8 * 200
    const int wgid = (orig & 7) * 200 + (orig >> 3);   // bijective XCD chunks
    const int ng = wgid / 25;
    const int tileS = (wgid - ng * 25) * 128;
    const int n = ng >> 1, g = ng & 1;
    const int wave = tid >> 6, lane = tid & 63;
    const int wm = (wave >> 1) * 64, wn = (wave & 1) * 64;

    const int rl = tid >> 3, q = tid & 7;
    const int swq = (q ^ (rl & 7)) * 8;     // pre-swizzled source chunk (shorts)

    const unsigned short* xpn = xp + (size_t)n * SPAD * 256 + g * 128 + swq;
    const unsigned short* arow[4];
    const unsigned short* brow[4];
#pragma unroll
    for (int p = 0; p < 4; ++p) {
        int s = tileS + p * 32 + rl;
        int sc = s < HWB ? s : HWB - 1;     // clamped rows feed discarded outputs
        int sp = sc + 2 * (sc / 56) + 59;
        arow[p] = xpn + (size_t)sp * 256;
        brow[p] = wp + (size_t)(g * 128 + p * 32 + rl) * 1152 + swq;
    }

    f32x4 acc[4][4] = {};
    const int frow = lane & 15, quad = lane >> 4, sw = frow & 7;
    int rofA[4], rofB[4];
#pragma unroll
    for (int i = 0; i < 4; ++i) {
        rofA[i] = (wm + i * 16 + frow) * 64;
        rofB[i] = (wn + i * 16 + frow) * 64;
    }
    const int ldst = (tid >> 3) * 64 + (tid & 7) * 8;  // == rl*64 + q*8

    {
        const int shift0 = (-59) * 256;   // tap 0: dy=-1,dx=-1, kc=0
#pragma unroll
        for (int p = 0; p < 4; ++p) {
            gl_lds16(arow[p] + shift0, &As[0][p * 2048 + ldst]);
            gl_lds16(brow[p], &Bs[0][p * 2048 + ldst]);
        }
    }
    __syncthreads();

    int cur = 0;
#pragma unroll
    for (int t = 0; t < 18; ++t) {
        if (t < 17) {
            const int tn = t + 1;
            const int tap = tn >> 1;
            const int shift = ((tap / 3 - 1) * 58 + (tap % 3 - 1)) * 256 + (tn & 1) * 64;
#pragma unroll
            for (int p = 0; p < 4; ++p) {
                gl_lds16(arow[p] + shift, &As[cur ^ 1][p * 2048 + ldst]);
                gl_lds16(brow[p] + tn * 64, &Bs[cur ^ 1][p * 2048 + ldst]);
            }
        }
        const short* Ab = As[cur];
        const short* Bb = Bs[cur];
#pragma unroll
        for (int h = 0; h < 2; ++h) {
            bf16x8 af[4], bfr[4];
#pragma unroll
            for (int i = 0; i < 4; ++i)
                af[i] = *(const bf16x8*)&Ab[rofA[i] + ((h * 4 + quad) ^ sw) * 8];
#pragma unroll
            for (int j = 0; j < 4; ++j)
                bfr[j] = *(const bf16x8*)&Bb[rofB[j] + ((h * 4 + quad) ^ sw) * 8];
#pragma unroll
            for (int i = 0; i < 4; ++i)
#pragma unroll
                for (int j = 0; j < 4; ++j)
                    acc[i][j] = __builtin_amdgcn_mfma_f32_16x16x32_bf16(af[i], bfr[j], acc[i][j], 0, 0, 0);
        }
        __syncthreads();
        cur ^= 1;
    }
    unsigned short* ob = t3cl + (size_t)n * HWPAD * 256 + g * 128;
#pragma unroll
    for (int i = 0; i < 4; ++i)
#pragma unroll
        for (int r = 0; r < 4; ++r) {
            int s = tileS + wm + i * 16 + (lane >> 4) * 4 + r;
            int c = wn + (lane & 15);
#pragma unroll
            for (int j = 0; j < 4; ++j) {
                float v = (s < HWB) ? acc[i][j][r] : 0.f;
                ob[(size_t)s * 256 + c + j * 16] = f2bf(v);
            }
        }
}

// ---------------------------------------------------------------------------
// GEMM1 (split-K=4, BK=64): part[z][m][e] = sum_k xc[m][k] p1t[e][k]
// Double-buffered staging; XCD swizzle.  z=0 -> 13 steps, z=1..3 -> 12.
// ---------------------------------------------------------------------------
__global__ __launch_bounds__(256) void k_gemm1(
    const unsigned short* __restrict__ xc, const unsigned short* __restrict__ p1t,
    float* __restrict__ part)
{
    __shared__ short As[2][128 * 64];
    __shared__ short Bs[2][128 * 64];
    const int tid = threadIdx.x;
    const int orig = blockIdx.x;                      // 512 = 8 * 64
    const int wgid = (orig & 7) * 64 + (orig >> 3);
    const int z = wgid >> 7;
    const int rem = wgid & 127;
    const int tileM = (rem >> 1) * 128;
    const int tileN = (rem & 1) * 128;
    const int kbase = z ? (832 + (z - 1) * 768) : 0;
    const int nk = z ? 12 : 13;
    const int wave = tid >> 6, lane = tid & 63;
    const int wm = (wave >> 1) * 64, wn = (wave & 1) * 64;

    const int rl = tid >> 3, q = tid & 7;
    const int swq = (q ^ (rl & 7)) * 8;
    const unsigned short* asrc = xc + (size_t)(tileM + rl) * HWB + kbase + swq;
    const unsigned short* bsrc = p1t + (size_t)(tileN + rl) * HWB + kbase + swq;

    f32x4 acc[4][4] = {};
    const int frow = lane & 15, quad = lane >> 4, sw = frow & 7;
    const int ldst = rl * 64 + q * 8;

#pragma unroll
    for (int p = 0; p < 4; ++p) {
        gl_lds16(asrc + (size_t)(p * 32) * HWB, &As[0][p * 2048 + ldst]);
        gl_lds16(bsrc + (size_t)(p * 32) * HWB, &Bs[0][p * 2048 + ldst]);
    }
    __syncthreads();

    int cur = 0;
    for (int i2 = 0; i2 < nk; ++i2) {
        if (i2 + 1 < nk) {
            const int kn = (i2 + 1) * 64;
#pragma unroll
            for (int p = 0; p < 4; ++p) {
                gl_lds16(asrc + (size_t)(p * 32) * HWB + kn, &As[cur ^ 1][p * 2048 + ldst]);
                gl_lds16(bsrc + (size_t)(p * 32) * HWB + kn, &Bs[cur ^ 1][p * 2048 + ldst]);
            }
        }
        const short* Ab = As[cur];
        const short* Bb = Bs[cur];
#pragma unroll
        for (int h = 0; h < 2; ++h) {
            bf16x8 af[4], bfr[4];
#pragma unroll
            for (int i = 0; i < 4; ++i)
                af[i] = *(const bf16x8*)&Ab[(wm + i * 16 + frow) * 64 + ((h * 4 + quad) ^ sw) * 8];
#pragma unroll
            for (int j = 0; j < 4; ++j)
                bfr[j] = *(const bf16x8*)&Bb[(wn + j * 16 + frow) * 64 + ((h * 4 + quad) ^ sw) * 8];
#pragma unroll
            for (int i = 0; i < 4; ++i)
#pragma unroll
                for (int j = 0; j < 4; ++j)
                    acc[i][j] = __builtin_amdgcn_mfma_f32_16x16x32_bf16(af[i], bfr[j], acc[i][j], 0, 0, 0);
        }
        __syncthreads();
        cur ^= 1;
    }
    float* ob = part + (size_t)z * 8192 * 256;
#pragma unroll
    for (int j = 0; j < 4; ++j) {
        const int e = tileN + wn + j * 16 + (lane & 15);
#pragma unroll
        for (int i = 0; i < 4; ++i)
#pragma unroll
            for (int r = 0; r < 4; ++r) {
                int m = tileM + wm + i * 16 + (lane >> 4) * 4 + r;
                ob[(size_t)m * 256 + e] = acc[i][j][r];
            }
    }
}

// ---------------------------------------------------------------------------
// t4scale: reduce 4 split-K slabs; t4h[m][e] = bf16(t1*p4); t5[m]=sum_e t4*p5
// ---------------------------------------------------------------------------
__global__ __launch_bounds__(256) void k_t4scale(
    const float* __restrict__ part, const float* __restrict__ p4,
    const float* __restrict__ p5, unsigned short* __restrict__ t4h,
    float* __restrict__ t5)
{
    const int row = blockIdx.x * 4 + (threadIdx.x >> 6);
    const int lane = threadIdx.x & 63;
    const size_t off = (size_t)row * 256 + lane * 4;
    const size_t slab = (size_t)8192 * 256;
    float4 a0 = *(const float4*)&part[off];
    float4 a1 = *(const float4*)&part[off + slab];
    float4 a2 = *(const float4*)&part[off + 2 * slab];
    float4 a3 = *(const float4*)&part[off + 3 * slab];
    float4 a;
    a.x = (a0.x + a1.x) + (a2.x + a3.x);
    a.y = (a0.y + a1.y) + (a2.y + a3.y);
    a.z = (a0.z + a1.z) + (a2.z + a3.z);
    a.w = (a0.w + a1.w) + (a2.w + a3.w);
    float4 sc = *(const float4*)&p4[(size_t)(row & 255) * 256 + lane * 4];
    float4 pv = *(const float4*)&p5[lane * 4];
    float v0 = a.x * sc.x, v1 = a.y * sc.y, v2 = a.z * sc.z, v3 = a.w * sc.w;
    ushort4 o;
    o.x = f2bf(v0); o.y = f2bf(v1); o.z = f2bf(v2); o.w = f2bf(v3);
    *(ushort4*)&t4h[(size_t)row * 256 + lane * 4] = o;
    float sum = v0 * pv.x + v1 * pv.y + v2 * pv.z + v3 * pv.w;
#pragma unroll
    for (int offd = 32; offd > 0; offd >>= 1) sum += __shfl_down(sum, offd);
    if (lane == 0) t5[row] = sum;
}

// ---------------------------------------------------------------------------
// BMM: out[n][a][s] = (sum_b t4h[n][a][b] * t3cl[n][s][b]) / 16 + t7[n][s]
// t7 computed in-kernel from xp (channels-last row dot t5), no t7 pass.
// XCD-swizzled grid; double-buffered staging.
// ---------------------------------------------------------------------------
__global__ __launch_bounds__(256) void k_bmm(
    const unsigned short* __restrict__ t4h, const unsigned short* __restrict__ t3cl,
    const unsigned short* __restrict__ xp, const float* __restrict__ t5,
    float* __restrict__ out)
{
    __shared__ short As[2][128 * 64];
    __shared__ short Bs[2][128 * 64];
    __shared__ float t5s[256];
    __shared__ float t7loc[128];
    const int tid = threadIdx.x;
    const int orig = blockIdx.x;                       // 1600 = 8 * 200
    const int wgid = (orig & 7) * 200 + (orig >> 3);
    const int n = wgid / 50;
    const int rem = wgid - n * 50;
    const int tileA = (rem / 25) * 128;
    const int tileS = (rem % 25) * 128;
    const int wave = tid >> 6, lane = tid & 63;
    const int wm = (wave >> 1) * 64, wn = (wave & 1) * 64;

    const int rl = tid >> 3, q = tid & 7;
    const int swq = (q ^ (rl & 7)) * 8;
    const unsigned short* asrc = t4h + ((size_t)n * 256 + tileA + rl) * 256 + swq;
    const unsigned short* bsrc = t3cl + ((size_t)n * HWPAD + tileS + rl) * 256 + swq;

    f32x4 acc[4][4] = {};
    const int frow = lane & 15, quad = lane >> 4, sw = frow & 7;
    const int ldst = rl * 64 + q * 8;

    t5s[tid] = t5[n * 256 + tid];
#pragma unroll
    for (int p = 0; p < 4; ++p) {
        gl_lds16(asrc + (size_t)(p * 32) * 256, &As[0][p * 2048 + ldst]);
        gl_lds16(bsrc + (size_t)(p * 32) * 256, &Bs[0][p * 2048 + ldst]);
    }
    __syncthreads();   // t5s visible; buf0 staged

    // t7 for this s-tile: t<128 each own one s
    if (tid < 128) {
        const int s = tileS + tid;
        float accv = 0.f;
        if (s < HWB) {
            const int sp = s + 2 * (s / 56) + 59;
            const unsigned short* row = xp + ((size_t)n * SPAD + sp) * 256;
#pragma unroll
            for (int j = 0; j < 32; ++j) {
                bf16x8 v = *(const bf16x8*)(row + j * 8);
#pragma unroll
                for (int k = 0; k < 8; ++k)
                    accv += t5s[j * 8 + k] * bf2f((unsigned short)v[k]);
            }
        }
        t7loc[tid] = accv * 0.0625f;
    }

    int cur = 0;
#pragma unroll
    for (int k0 = 0; k0 < 256; k0 += 64) {
        if (k0 < 192) {
            const int kn = k0 + 64;
#pragma unroll
            for (int p = 0; p < 4; ++p) {
                gl_lds16(asrc + (size_t)(p * 32) * 256 + kn, &As[cur ^ 1][p * 2048 + ldst]);
                gl_lds16(bsrc + (size_t)(p * 32) * 256 + kn, &Bs[cur ^ 1][p * 2048 + ldst]);
            }
        }
        const short* Ab = As[cur];
        const short* Bb = Bs[cur];
#pragma unroll
        for (int h = 0; h < 2; ++h) {
            bf16x8 af[4], bfr[4];
#pragma unroll
            for (int i = 0; i < 4; ++i)
                af[i] = *(const bf16x8*)&Ab[(wm + i * 16 + frow) * 64 + ((h * 4 + quad) ^ sw) * 8];
#pragma unroll
            for (int j = 0; j < 4; ++j)
                bfr[j] = *(const bf16x8*)&Bb[(wn + j * 16 + frow) * 64 + ((h * 4 + quad) ^ sw) * 8];
#pragma unroll
            for (int i = 0; i < 4; ++i)
#pragma unroll
                for (int j = 0; j < 4; ++j)
                    acc[i][j] = __builtin_amdgcn_mfma_f32_16x16x32_bf16(af[i], bfr[j], acc[i][j], 0, 0, 0);
        }
        __syncthreads();
        cur ^= 1;
    }
    float* ob = out + (size_t)n * 256 * HWB;
#pragma unroll
    for (int j = 0; j < 4; ++j) {
        const int sLoc = wn + j * 16 + (lane & 15);
        const int s = tileS + sLoc;
        if (s >= HWB) continue;
        const float t7v = t7loc[sLoc];
#pragma unroll
        for (int i = 0; i < 4; ++i)
#pragma unroll
            for (int r = 0; r < 4; ++r) {
                int a = tileA + wm + i * 16 + (lane >> 4) * 4 + r;
                ob[(size_t)a * HWB + s] = acc[i][j][r] * 0.0625f + t7v;
            }
    }
}

extern "C" void kernel_launch(void* const* d_in, const int* in_sizes, int n_in,
                              void* d_out, int out_size, void* d_ws, size_t ws_size,
                              hipStream_t stream) {
    const float* x  = (const float*)d_in[0];
    const float* p1 = (const float*)d_in[1];
    const float* cw = (const float*)d_in[2];
    const float* p4 = (const float*)d_in[3];
    const float* p5 = (const float*)d_in[4];

    char* w = (char*)d_ws;
    unsigned short* xp    = (unsigned short*)w;  w += (size_t)32 * SPAD * 256 * 2;   // 55.1 MB
    unsigned short* t3cl  = (unsigned short*)w;  w += (size_t)32 * HWPAD * 256 * 2;  // 52.4 MB
    unsigned short* p1t   = (unsigned short*)w;  w += (size_t)256 * HWB * 2;
    unsigned short* wpack = (unsigned short*)w;  w += (size_t)256 * 1152 * 2;
    unsigned short* t4h   = (unsigned short*)w;  w += (size_t)8192 * 256 * 2;
    float* t5             = (float*)w;           w += (size_t)8192 * 4;

    // d_out doubles as scratch; all scratch consumers (gemm1 reads xc,
    // t4scale reads part) finish before k_bmm overwrites d_out:
    //   xc   [32][256][3136] bf16 = 51,380,224 B
    //   part [4][8192][256]  f32  = 33,554,432 B  (total 84.9 MB <= 102.8 MB)
    char* o = (char*)d_out;
    unsigned short* xc = (unsigned short*)o;
    float* part        = (float*)(o + (size_t)32 * 256 * HWB * 2);
    float* out = (float*)d_out;

    k_misc    <<<dim3(1968),      256, 0, stream>>>(p1, cw, p1t, wpack, xp);
    k_prep    <<<dim3(49, 4, 32), 256, 0, stream>>>(x, xc, xp);
    k_conv    <<<dim3(1600),      256, 0, stream>>>(xp, wpack, t3cl);
    k_gemm1   <<<dim3(512),       256, 0, stream>>>(xc, p1t, part);
    k_t4scale <<<dim3(2048),      256, 0, stream>>>(part, p4, p5, t4h, t5);
    k_bmm     <<<dim3(1600),      256, 0, stream>>>(t4h, t3cl, xp, t5, out);
}

// Round 6
// 329.857 us; speedup vs baseline: 1.2294x; 1.0448x over previous
//
#include <hip/hip_runtime.h>

#define HWB   3136
#define HWPAD 3200
#define SPAD  3364   // 58*58 zero-padded spatial

typedef __attribute__((ext_vector_type(8))) short bf16x8;
typedef __attribute__((ext_vector_type(4))) float f32x4;

__device__ __forceinline__ unsigned short f2bf(float f) {
    unsigned u = __float_as_uint(f);
    unsigned r = (u + 0x7fffu + ((u >> 16) & 1u)) >> 16;
    return (unsigned short)r;
}
__device__ __forceinline__ float bf2f(unsigned short h) {
    return __uint_as_float(((unsigned)h) << 16);
}
__device__ __forceinline__ void gl_lds16(const void* g, void* l) {
    __builtin_amdgcn_global_load_lds(
        (const __attribute__((address_space(1))) void*)g,
        (__attribute__((address_space(3))) void*)l, 16, 0, 0);
}

// ---------------------------------------------------------------------------
// Merged prep (one dispatch, 8240 blocks):
//  [0,6272):    x f32 -> xc bf16 (same layout) + xp bf16 (padded ch-last).
//               64c x 64s tile; channel-PAIR threads; LDS dword stride 33
//               -> both transpose sides are perfect 2-way (conflict-free).
//  [6272,7056): p1 [3136][256] -> p1t [256][3136] bf16 transpose.
//  [7056,7312): conv_w -> wpack [o][tap*128+ci] bf16.
//  [7312,8240): zero the 228 border rows of xp per image.
// ---------------------------------------------------------------------------
__global__ __launch_bounds__(256) void k_prep(
    const float* __restrict__ x, unsigned short* __restrict__ xc,
    unsigned short* __restrict__ xp,
    const float* __restrict__ p1, const float* __restrict__ cw,
    unsigned short* __restrict__ p1t, unsigned short* __restrict__ wp)
{
    const int b = blockIdx.x, t = threadIdx.x;
    if (b < 6272) {
        __shared__ unsigned tile[64 * 33];     // dwords = channel pairs
        const int n = b / 196, rem = b - n * 196;
        const int c0 = (rem / 49) * 64, s0 = (rem % 49) * 64;
        const int cp = t >> 3;                 // 0..31 channel pair
        const int sg = (t & 7) * 8;            // s offset within tile

        const float* src = x + ((size_t)(n * 256 + c0 + 2 * cp)) * HWB + s0 + sg;
        unsigned short b0[8], b1[8];
        {
            float4 v0 = *(const float4*)(src);
            float4 v1 = *(const float4*)(src + 4);
            float4 w0 = *(const float4*)(src + HWB);
            float4 w1 = *(const float4*)(src + HWB + 4);
            b0[0] = f2bf(v0.x); b0[1] = f2bf(v0.y); b0[2] = f2bf(v0.z); b0[3] = f2bf(v0.w);
            b0[4] = f2bf(v1.x); b0[5] = f2bf(v1.y); b0[6] = f2bf(v1.z); b0[7] = f2bf(v1.w);
            b1[0] = f2bf(w0.x); b1[1] = f2bf(w0.y); b1[2] = f2bf(w0.z); b1[3] = f2bf(w0.w);
            b1[4] = f2bf(w1.x); b1[5] = f2bf(w1.y); b1[6] = f2bf(w1.z); b1[7] = f2bf(w1.w);
        }
        unsigned short* xcb = xc + ((size_t)(n * 256 + c0 + 2 * cp)) * HWB + s0 + sg;
        *(bf16x8*)xcb = *(const bf16x8*)&b0[0];
        *(bf16x8*)(xcb + HWB) = *(const bf16x8*)&b1[0];
#pragma unroll
        for (int k = 0; k < 8; ++k)
            tile[(sg + k) * 33 + cp] = (unsigned)b0[k] | ((unsigned)b1[k] << 16);
        __syncthreads();
        const int r = t >> 2;                  // 0..63 local s row
        const int cq = (t & 3) * 8;            // dword col base 0/8/16/24
        unsigned d[8];
#pragma unroll
        for (int j = 0; j < 8; ++j)
            d[j] = tile[r * 33 + cq + j];
        const int s = s0 + r;
        const int sp = s + 2 * (s / 56) + 59;  // (y+1)*58 + (x+1)
        unsigned* dst = (unsigned*)(xp + ((size_t)n * SPAD + sp) * 256 + c0 + 2 * cq);
        *(uint4*)dst = make_uint4(d[0], d[1], d[2], d[3]);
        *(uint4*)(dst + 4) = make_uint4(d[4], d[5], d[6], d[7]);
    } else if (b < 7056) {
        __shared__ unsigned short tile[32][33];
        const int b2 = b - 6272;
        const int h0 = (b2 % 98) * 32, e0 = (b2 / 98) * 32;
        const int lx = t & 31, ly = t >> 5;
#pragma unroll
        for (int it = 0; it < 4; ++it) {
            int lh = ly + it * 8;
            tile[lh][lx] = f2bf(p1[(size_t)(h0 + lh) * 256 + e0 + lx]);
        }
        __syncthreads();
#pragma unroll
        for (int it = 0; it < 4; ++it) {
            int le = ly + it * 8;
            p1t[(size_t)(e0 + le) * HWB + h0 + lx] = tile[lx][le];
        }
    } else if (b < 7312) {
        const int o = b - 7056;
#pragma unroll
        for (int k = t; k < 1152; k += 256) {
            int tap = k >> 7, ci = k & 127;
            wp[(size_t)o * 1152 + k] = f2bf(cw[(size_t)o * 1152 + ci * 9 + tap]);
        }
    } else {
        const int bb = b - 7312;               // 0..927 = 32n * 29 chunks
        const int n = bb / 29, xb = bb - n * 29;
        const int idx = xb * 256 + t;
        if (idx < 228 * 32) {
            const int i = idx >> 5, ch = idx & 31;
            int sp;
            if (i < 58)       sp = i;                        // y = 0
            else if (i < 116) sp = 3306 + (i - 58);          // y = 57
            else if (i < 172) sp = (i - 115) * 58;           // x = 0
            else              sp = (i - 171) * 58 + 57;      // x = 57
            bf16x8 z = {};
            *(bf16x8*)&xp[((size_t)n * SPAD + sp) * 256 + ch * 8] = z;
        }
    }
}

// ---------------------------------------------------------------------------
// Merged MFMA dispatch (1856 blocks):
//  [0,1600):    grouped 3x3 conv GEMM per (n,g), K=1152, XCD-swizzled,
//               double-buffered LDS (the proven 76us kernel, unchanged).
//  [1600,1856): GEMM1 split-K=2: part[z][m][e] = sum_k xc[m][k] p1t[e][k],
//               z=0 -> 25 K-steps, z=1 -> 24.
// ---------------------------------------------------------------------------
__global__ __launch_bounds__(256) void k_mfma(
    const unsigned short* __restrict__ xp, const unsigned short* __restrict__ wp,
    unsigned short* __restrict__ t3cl,
    const unsigned short* __restrict__ xc, const unsigned short* __restrict__ p1t,
    float* __restrict__ part)
{
    __shared__ short As[2][128 * 64];
    __shared__ short Bs[2][128 * 64];
    const int tid = threadIdx.x;
    const int wave = tid >> 6, lane = tid & 63;
    const int wm = (wave >> 1) * 64, wn = (wave & 1) * 64;
    const int rl = tid >> 3, q = tid & 7;
    const int swq = (q ^ (rl & 7)) * 8;
    const int ldst = rl * 64 + q * 8;
    const int frow = lane & 15, quad = lane >> 4, sw = frow & 7;

    if (blockIdx.x < 1600) {
        // ----- conv -----
        const int orig = blockIdx.x;                       // 1600 = 8 * 200
        const int wgid = (orig & 7) * 200 + (orig >> 3);
        const int ng = wgid / 25;
        const int tileS = (wgid - ng * 25) * 128;
        const int n = ng >> 1, g = ng & 1;

        const unsigned short* xpn = xp + (size_t)n * SPAD * 256 + g * 128 + swq;
        const unsigned short* arow[4];
        const unsigned short* brow[4];
#pragma unroll
        for (int p = 0; p < 4; ++p) {
            int s = tileS + p * 32 + rl;
            int sc = s < HWB ? s : HWB - 1;
            int sp = sc + 2 * (sc / 56) + 59;
            arow[p] = xpn + (size_t)sp * 256;
            brow[p] = wp + (size_t)(g * 128 + p * 32 + rl) * 1152 + swq;
        }

        f32x4 acc[4][4] = {};
        int rofA[4], rofB[4];
#pragma unroll
        for (int i = 0; i < 4; ++i) {
            rofA[i] = (wm + i * 16 + frow) * 64;
            rofB[i] = (wn + i * 16 + frow) * 64;
        }
        {
            const int shift0 = (-59) * 256;
#pragma unroll
            for (int p = 0; p < 4; ++p) {
                gl_lds16(arow[p] + shift0, &As[0][p * 2048 + ldst]);
                gl_lds16(brow[p], &Bs[0][p * 2048 + ldst]);
            }
        }
        __syncthreads();

        int cur = 0;
#pragma unroll
        for (int t = 0; t < 18; ++t) {
            if (t < 17) {
                const int tn = t + 1;
                const int tap = tn >> 1;
                const int shift = ((tap / 3 - 1) * 58 + (tap % 3 - 1)) * 256 + (tn & 1) * 64;
#pragma unroll
                for (int p = 0; p < 4; ++p) {
                    gl_lds16(arow[p] + shift, &As[cur ^ 1][p * 2048 + ldst]);
                    gl_lds16(brow[p] + tn * 64, &Bs[cur ^ 1][p * 2048 + ldst]);
                }
            }
            const short* Ab = As[cur];
            const short* Bb = Bs[cur];
#pragma unroll
            for (int h = 0; h < 2; ++h) {
                bf16x8 af[4], bfr[4];
#pragma unroll
                for (int i = 0; i < 4; ++i)
                    af[i] = *(const bf16x8*)&Ab[rofA[i] + ((h * 4 + quad) ^ sw) * 8];
#pragma unroll
                for (int j = 0; j < 4; ++j)
                    bfr[j] = *(const bf16x8*)&Bb[rofB[j] + ((h * 4 + quad) ^ sw) * 8];
#pragma unroll
                for (int i = 0; i < 4; ++i)
#pragma unroll
                    for (int j = 0; j < 4; ++j)
                        acc[i][j] = __builtin_amdgcn_mfma_f32_16x16x32_bf16(af[i], bfr[j], acc[i][j], 0, 0, 0);
            }
            __syncthreads();
            cur ^= 1;
        }
        unsigned short* ob = t3cl + (size_t)n * HWPAD * 256 + g * 128;
#pragma unroll
        for (int i = 0; i < 4; ++i)
#pragma unroll
            for (int r = 0; r < 4; ++r) {
                int s = tileS + wm + i * 16 + quad * 4 + r;
                int c = wn + frow;
#pragma unroll
                for (int j = 0; j < 4; ++j) {
                    float v = (s < HWB) ? acc[i][j][r] : 0.f;
                    ob[(size_t)s * 256 + c + j * 16] = f2bf(v);
                }
            }
    } else {
        // ----- gemm1 (split-K = 2) -----
        const int orig = blockIdx.x - 1600;               // 256 = 8 * 32
        const int wgid = (orig & 7) * 32 + (orig >> 3);
        const int z = wgid >> 7;
        const int rem = wgid & 127;
        const int tileM = (rem >> 1) * 128;
        const int tileN = (rem & 1) * 128;
        const int kbase = z * 1600;
        const int nk = z ? 24 : 25;

        const unsigned short* asrc = xc + (size_t)(tileM + rl) * HWB + kbase + swq;
        const unsigned short* bsrc = p1t + (size_t)(tileN + rl) * HWB + kbase + swq;

        f32x4 acc[4][4] = {};
#pragma unroll
        for (int p = 0; p < 4; ++p) {
            gl_lds16(asrc + (size_t)(p * 32) * HWB, &As[0][p * 2048 + ldst]);
            gl_lds16(bsrc + (size_t)(p * 32) * HWB, &Bs[0][p * 2048 + ldst]);
        }
        __syncthreads();

        int cur = 0;
        for (int i2 = 0; i2 < nk; ++i2) {
            if (i2 + 1 < nk) {
                const int kn = (i2 + 1) * 64;
#pragma unroll
                for (int p = 0; p < 4; ++p) {
                    gl_lds16(asrc + (size_t)(p * 32) * HWB + kn, &As[cur ^ 1][p * 2048 + ldst]);
                    gl_lds16(bsrc + (size_t)(p * 32) * HWB + kn, &Bs[cur ^ 1][p * 2048 + ldst]);
                }
            }
            const short* Ab = As[cur];
            const short* Bb = Bs[cur];
#pragma unroll
            for (int h = 0; h < 2; ++h) {
                bf16x8 af[4], bfr[4];
#pragma unroll
                for (int i = 0; i < 4; ++i)
                    af[i] = *(const bf16x8*)&Ab[(wm + i * 16 + frow) * 64 + ((h * 4 + quad) ^ sw) * 8];
#pragma unroll
                for (int j = 0; j < 4; ++j)
                    bfr[j] = *(const bf16x8*)&Bb[(wn + j * 16 + frow) * 64 + ((h * 4 + quad) ^ sw) * 8];
#pragma unroll
                for (int i = 0; i < 4; ++i)
#pragma unroll
                    for (int j = 0; j < 4; ++j)
                        acc[i][j] = __builtin_amdgcn_mfma_f32_16x16x32_bf16(af[i], bfr[j], acc[i][j], 0, 0, 0);
            }
            __syncthreads();
            cur ^= 1;
        }
        float* ob = part + (size_t)z * 8192 * 256;
#pragma unroll
        for (int j = 0; j < 4; ++j) {
            const int e = tileN + wn + j * 16 + frow;
#pragma unroll
            for (int i = 0; i < 4; ++i)
#pragma unroll
                for (int r = 0; r < 4; ++r) {
                    int m = tileM + wm + i * 16 + quad * 4 + r;
                    ob[(size_t)m * 256 + e] = acc[i][j][r];
                }
        }
    }
}

// ---------------------------------------------------------------------------
// t4scale: reduce 2 split-K slabs; t4h[m][e] = bf16(t1*p4); t5[m]=sum_e t4*p5
// ---------------------------------------------------------------------------
__global__ __launch_bounds__(256) void k_t4scale(
    const float* __restrict__ part, const float* __restrict__ p4,
    const float* __restrict__ p5, unsigned short* __restrict__ t4h,
    float* __restrict__ t5)
{
    const int row = blockIdx.x * 4 + (threadIdx.x >> 6);
    const int lane = threadIdx.x & 63;
    const size_t off = (size_t)row * 256 + lane * 4;
    const size_t slab = (size_t)8192 * 256;
    float4 a0 = *(const float4*)&part[off];
    float4 a1 = *(const float4*)&part[off + slab];
    float4 a;
    a.x = a0.x + a1.x; a.y = a0.y + a1.y; a.z = a0.z + a1.z; a.w = a0.w + a1.w;
    float4 sc = *(const float4*)&p4[(size_t)(row & 255) * 256 + lane * 4];
    float4 pv = *(const float4*)&p5[lane * 4];
    float v0 = a.x * sc.x, v1 = a.y * sc.y, v2 = a.z * sc.z, v3 = a.w * sc.w;
    ushort4 o;
    o.x = f2bf(v0); o.y = f2bf(v1); o.z = f2bf(v2); o.w = f2bf(v3);
    *(ushort4*)&t4h[(size_t)row * 256 + lane * 4] = o;
    float sum = v0 * pv.x + v1 * pv.y + v2 * pv.z + v3 * pv.w;
#pragma unroll
    for (int offd = 32; offd > 0; offd >>= 1) sum += __shfl_down(sum, offd);
    if (lane == 0) t5[row] = sum;
}

// ---------------------------------------------------------------------------
// BMM: out[n][a][s] = (sum_b t4h[n][a][b] * t3cl[n][s][b]) / 16 + t7[n][s]
// t7 computed in-kernel from xp row dot t5.  XCD-swizzled; double-buffered.
// ---------------------------------------------------------------------------
__global__ __launch_bounds__(256) void k_bmm(
    const unsigned short* __restrict__ t4h, const unsigned short* __restrict__ t3cl,
    const unsigned short* __restrict__ xp, const float* __restrict__ t5,
    float* __restrict__ out)
{
    __shared__ short As[2][128 * 64];
    __shared__ short Bs[2][128 * 64];
    __shared__ float t5s[256];
    __shared__ float t7loc[128];
    const int tid = threadIdx.x;
    const int orig = blockIdx.x;                       // 1600 = 8 * 200
    const int wgid = (orig & 7) * 200 + (orig >> 3);
    const int n = wgid / 50;
    const int rem = wgid - n * 50;
    const int tileA = (rem / 25) * 128;
    const int tileS = (rem % 25) * 128;
    const int wave = tid >> 6, lane = tid & 63;
    const int wm = (wave >> 1) * 64, wn = (wave & 1) * 64;

    const int rl = tid >> 3, q = tid & 7;
    const int swq = (q ^ (rl & 7)) * 8;
    const unsigned short* asrc = t4h + ((size_t)n * 256 + tileA + rl) * 256 + swq;
    const unsigned short* bsrc = t3cl + ((size_t)n * HWPAD + tileS + rl) * 256 + swq;

    f32x4 acc[4][4] = {};
    const int frow = lane & 15, quad = lane >> 4, sw = frow & 7;
    const int ldst = rl * 64 + q * 8;

    t5s[tid] = t5[n * 256 + tid];
#pragma unroll
    for (int p = 0; p < 4; ++p) {
        gl_lds16(asrc + (size_t)(p * 32) * 256, &As[0][p * 2048 + ldst]);
        gl_lds16(bsrc + (size_t)(p * 32) * 256, &Bs[0][p * 2048 + ldst]);
    }
    __syncthreads();   // t5s visible; buf0 staged

    if (tid < 128) {
        const int s = tileS + tid;
        float accv = 0.f;
        if (s < HWB) {
            const int sp = s + 2 * (s / 56) + 59;
            const unsigned short* row = xp + ((size_t)n * SPAD + sp) * 256;
#pragma unroll
            for (int j = 0; j < 32; ++j) {
                bf16x8 v = *(const bf16x8*)(row + j * 8);
#pragma unroll
                for (int k = 0; k < 8; ++k)
                    accv += t5s[j * 8 + k] * bf2f((unsigned short)v[k]);
            }
        }
        t7loc[tid] = accv * 0.0625f;
    }

    int cur = 0;
#pragma unroll
    for (int k0 = 0; k0 < 256; k0 += 64) {
        if (k0 < 192) {
            const int kn = k0 + 64;
#pragma unroll
            for (int p = 0; p < 4; ++p) {
                gl_lds16(asrc + (size_t)(p * 32) * 256 + kn, &As[cur ^ 1][p * 2048 + ldst]);
                gl_lds16(bsrc + (size_t)(p * 32) * 256 + kn, &Bs[cur ^ 1][p * 2048 + ldst]);
            }
        }
        const short* Ab = As[cur];
        const short* Bb = Bs[cur];
#pragma unroll
        for (int h = 0; h < 2; ++h) {
            bf16x8 af[4], bfr[4];
#pragma unroll
            for (int i = 0; i < 4; ++i)
                af[i] = *(const bf16x8*)&Ab[(wm + i * 16 + frow) * 64 + ((h * 4 + quad) ^ sw) * 8];
#pragma unroll
            for (int j = 0; j < 4; ++j)
                bfr[j] = *(const bf16x8*)&Bb[(wn + j * 16 + frow) * 64 + ((h * 4 + quad) ^ sw) * 8];
#pragma unroll
            for (int i = 0; i < 4; ++i)
#pragma unroll
                for (int j = 0; j < 4; ++j)
                    acc[i][j] = __builtin_amdgcn_mfma_f32_16x16x32_bf16(af[i], bfr[j], acc[i][j], 0, 0, 0);
        }
        __syncthreads();
        cur ^= 1;
    }
    float* ob = out + (size_t)n * 256 * HWB;
#pragma unroll
    for (int j = 0; j < 4; ++j) {
        const int sLoc = wn + j * 16 + frow;
        const int s = tileS + sLoc;
        if (s >= HWB) continue;
        const float t7v = t7loc[sLoc];
#pragma unroll
        for (int i = 0; i < 4; ++i)
#pragma unroll
            for (int r = 0; r < 4; ++r) {
                int a = tileA + wm + i * 16 + quad * 4 + r;
                ob[(size_t)a * HWB + s] = acc[i][j][r] * 0.0625f + t7v;
            }
    }
}

extern "C" void kernel_launch(void* const* d_in, const int* in_sizes, int n_in,
                              void* d_out, int out_size, void* d_ws, size_t ws_size,
                              hipStream_t stream) {
    const float* x  = (const float*)d_in[0];
    const float* p1 = (const float*)d_in[1];
    const float* cw = (const float*)d_in[2];
    const float* p4 = (const float*)d_in[3];
    const float* p5 = (const float*)d_in[4];

    char* w = (char*)d_ws;
    unsigned short* xp    = (unsigned short*)w;  w += (size_t)32 * SPAD * 256 * 2;   // 55.1 MB
    unsigned short* t3cl  = (unsigned short*)w;  w += (size_t)32 * HWPAD * 256 * 2;  // 52.4 MB
    unsigned short* p1t   = (unsigned short*)w;  w += (size_t)256 * HWB * 2;
    unsigned short* wpack = (unsigned short*)w;  w += (size_t)256 * 1152 * 2;
    unsigned short* t4h   = (unsigned short*)w;  w += (size_t)8192 * 256 * 2;
    float* t5             = (float*)w;           w += (size_t)8192 * 4;

    // d_out doubles as scratch; all scratch consumers (k_mfma reads xc,
    // t4scale reads part) finish before k_bmm overwrites d_out:
    //   xc   [32][256][3136] bf16 = 51,380,224 B
    //   part [2][8192][256]  f32  = 16,777,216 B  (total 68.2 MB <= 102.8 MB)
    char* o = (char*)d_out;
    unsigned short* xc = (unsigned short*)o;
    float* part        = (float*)(o + (size_t)32 * 256 * HWB * 2);
    float* out = (float*)d_out;

    k_prep    <<<dim3(8240),  256, 0, stream>>>(x, xc, xp, p1, cw, p1t, wpack);
    k_mfma    <<<dim3(1856),  256, 0, stream>>>(xp, wpack, t3cl, xc, p1t, part);
    k_t4scale <<<dim3(2048),  256, 0, stream>>>(part, p4, p5, t4h, t5);
    k_bmm     <<<dim3(1600),  256, 0, stream>>>(t4h, t3cl, xp, t5, out);
}